// Round 2
// baseline (568.326 us; speedup 1.0000x reference)
//
#include <hip/hip_runtime.h>
#include <stdint.h>

typedef unsigned long long u64;
typedef unsigned int u32;

#define NCLS 80
#define NA   8400
#define NIMG 32
#define TOPK 1500
#define MAXDET 300
#define NW 24              // ceil(1500/64) words per suppression row
#define SORTN 16384
#define CONF 0.25f
#define IOU_TH 0.45f

// ---- workspace layout (bytes) ----
#define OFF_KEYS   ((size_t)0)                            // NIMG*NA*8
#define OFF_CLS    (OFF_KEYS + (size_t)NIMG*NA*8)         // NIMG*NA*4
#define OFF_TBOX   (OFF_CLS  + (size_t)NIMG*NA*4)         // NIMG*TOPK*16 (float4)
#define OFF_TNMS   (OFF_TBOX + (size_t)NIMG*TOPK*16)      // NIMG*TOPK*16 (float4)
#define OFF_TSC    (OFF_TNMS + (size_t)NIMG*TOPK*16)      // NIMG*TOPK*4
#define OFF_TCL    (OFF_TSC  + (size_t)NIMG*TOPK*4)       // NIMG*TOPK*4
#define OFF_MASK   (OFF_TCL  + (size_t)NIMG*TOPK*4)       // NIMG*TOPK*NW*8
#define WS_NEED    (OFF_MASK + (size_t)NIMG*TOPK*NW*8)    // ~14.4 MB

// ---------------------------------------------------------------------------
// Kernel 1: per-anchor class max/argmax, build sort key.
// key = (~ordered(msc) << 32) | anchor  ->  ascending sort == descending score,
// ties broken by lower anchor index (exactly lax.top_k semantics).
// ---------------------------------------------------------------------------
__global__ __launch_bounds__(256) void k_score(const float* __restrict__ pred,
                                               int* __restrict__ cls,
                                               u64* __restrict__ keys) {
    int a = blockIdx.x * 256 + threadIdx.x;
    int b = blockIdx.y;
    if (a >= NA) return;
    const float* pb = pred + (size_t)b * (4 + NCLS) * NA;
    float best = pb[(size_t)4 * NA + a];
    int bi = 0;
#pragma unroll 8
    for (int c = 1; c < NCLS; ++c) {
        float v = pb[(size_t)(4 + c) * NA + a];
        if (v > best) { best = v; bi = c; }     // strict > : first max wins (jnp.argmax)
    }
    cls[b * NA + a] = bi;
    float msc = (best > CONF) ? best : -1.0f;
    u32 u = __float_as_uint(msc);
    u = (u & 0x80000000u) ? ~u : (u | 0x80000000u);   // order-preserving map
    keys[(size_t)b * NA + a] = ((u64)(~u) << 32) | (u32)a;
}

// ---------------------------------------------------------------------------
// Kernel 2: per-image bitonic sort of 16384-padded keys in LDS, then gather
// top-1500: original box, class-offset nms box, score, class.
// fp contract OFF: nmsbox mul+add must round exactly like XLA's separate ops
// (an FMA here can flip a borderline iou>0.45 later).
// ---------------------------------------------------------------------------
__global__ __launch_bounds__(1024) void k_sort_gather(const float* __restrict__ pred,
                                                      const int* __restrict__ cls,
                                                      const u64* __restrict__ keys,
                                                      float4* __restrict__ tbox,
                                                      float4* __restrict__ tnms,
                                                      float* __restrict__ tsc,
                                                      int* __restrict__ tcl) {
#pragma clang fp contract(off)
    __shared__ u64 s[SORTN];                     // 128 KiB
    const int tid = threadIdx.x;
    const int b = blockIdx.x;
    const u64* kb = keys + (size_t)b * NA;
    for (int i = tid; i < SORTN; i += 1024)
        s[i] = (i < NA) ? kb[i] : ~0ULL;
    __syncthreads();

    for (u32 k = 2; k <= SORTN; k <<= 1) {
        for (u32 j = k >> 1; j > 0; j >>= 1) {
            for (int t = tid; t < SORTN / 2; t += 1024) {
                int i = 2 * t - (t & (j - 1));   // index with bit j clear
                u64 x = s[i], y = s[i + j];
                bool asc = (i & k) == 0;
                if ((x > y) == asc) { s[i] = y; s[i + j] = x; }
            }
            __syncthreads();
        }
    }

    const float* pb = pred + (size_t)b * (4 + NCLS) * NA;
    const float C1 = (float)((1.0 / 80.0) / 640.0);   // mult / IMGSZ
    const float C2 = (float)(1.0 / 80.0);             // mult
    for (int r = tid; r < TOPK; r += 1024) {
        u64 key = s[r];
        int a = (int)(key & 0xFFFFFFFFu);
        // recover msc from key high word
        u32 ou = ~((u32)(key >> 32));
        u32 fb = (ou & 0x80000000u) ? (ou ^ 0x80000000u) : ~ou;
        float msc = __uint_as_float(fb);
        int c = cls[b * NA + a];
        float x1 = pb[a], y1 = pb[NA + a], x2 = pb[2 * NA + a], y2 = pb[3 * NA + a];
        float off = (float)c * C2;
        tbox[b * TOPK + r] = make_float4(x1, y1, x2, y2);
        tnms[b * TOPK + r] = make_float4(x1 * C1 + off, y1 * C1 + off,
                                         x2 * C1 + off, y2 * C1 + off);
        tsc[b * TOPK + r] = msc;                 // == raw score whenever valid
        tcl[b * TOPK + r] = c;
    }
}

// ---------------------------------------------------------------------------
// Kernel 3: suppression bit matrix. mask[i][w] bit l = (iou(i, w*64+l) > TH)
// for j > i. grid (12, NIMG), 125 rows per block, nms boxes cached in LDS.
// fp contract OFF: area/inter mul feeding adds must not fuse to FMA (XLA
// rounds each op separately; a fused denominator can flip iou>0.45).
// ---------------------------------------------------------------------------
__global__ __launch_bounds__(256) void k_mask(const float4* __restrict__ tnms,
                                              u64* __restrict__ mask) {
#pragma clang fp contract(off)
    __shared__ float4 nb[TOPK];                  // 24 KB
    const int b = blockIdx.y;
    const int tid = threadIdx.x;
    for (int i = tid; i < TOPK; i += 256) nb[i] = tnms[b * TOPK + i];
    __syncthreads();

    const int row0 = blockIdx.x * 125;
    for (int item = tid; item < 125 * NW; item += 256) {
        int r = row0 + item / NW;
        int w = item % NW;
        u64 bits = 0ULL;
        if (w * 64 + 63 > r) {                   // word has any j > r
            float4 bi = nb[r];
            float area_i = (bi.z - bi.x) * (bi.w - bi.y);
            int jmax = min(64, TOPK - w * 64);
            for (int l = 0; l < jmax; ++l) {
                int j = w * 64 + l;
                if (j > r) {
                    float4 bj = nb[j];
                    float lx = fmaxf(bi.x, bj.x), ly = fmaxf(bi.y, bj.y);
                    float rx = fminf(bi.z, bj.z), ry = fminf(bi.w, bj.w);
                    float iw = fmaxf(rx - lx, 0.0f), ih = fmaxf(ry - ly, 0.0f);
                    float inter = iw * ih;
                    float area_j = (bj.z - bj.x) * (bj.w - bj.y);
                    float iou = inter / (area_i + area_j - inter + 1e-7f);
                    if (iou > IOU_TH) bits |= (1ULL << l);
                }
            }
        }
        mask[((size_t)b * TOPK + r) * NW + w] = bits;
    }
}

// ---------------------------------------------------------------------------
// Kernel 4: per-image serial greedy scan (1 wave). Lane w owns supp word w.
// supp initialized to ~valid so keep_i = !bit(supp,i) is the full condition.
// Mask rows prefetched in 10-row double-buffered register chunks.
// Then popcount prefix-sum compaction -> first min(kept,300) rows; rest zero.
// ---------------------------------------------------------------------------
__global__ __launch_bounds__(64) void k_scan(const u64* __restrict__ mask,
                                             const float4* __restrict__ tbox,
                                             const float* __restrict__ tsc,
                                             const int* __restrict__ tcl,
                                             float* __restrict__ out) {
    const int b = blockIdx.x;
    const int lane = threadIdx.x;
    float* outb = out + (size_t)b * MAXDET * 6;
    for (int i = lane; i < MAXDET * 6; i += 64) outb[i] = 0.0f;
    __syncthreads();   // drains stores: zero-fill ordered before detection writes

    // valid bitset: bit j of word `lane` (lanes 0..23)
    u64 validw = 0ULL;
    const bool act = lane < NW;
    if (act) {
        for (int l = 0; l < 64; ++l) {
            int j = lane * 64 + l;
            if (j < TOPK && tsc[b * TOPK + j] > CONF) validw |= (1ULL << l);
        }
    }
    u64 supp = ~validw;                          // invalid (and j>=1500) pre-suppressed

    const u64* mrow = mask + (size_t)b * TOPK * NW;
    u64 bufA[10], bufB[10];
#pragma unroll
    for (int t = 0; t < 10; ++t) bufA[t] = act ? mrow[(size_t)t * NW + lane] : 0ULL;

    for (int cc = 0; cc < 75; ++cc) {
        const int baseA = cc * 20;
        const int baseB = baseA + 10;
#pragma unroll
        for (int t = 0; t < 10; ++t)
            bufB[t] = act ? mrow[(size_t)(baseB + t) * NW + lane] : 0ULL;
#pragma unroll
        for (int t = 0; t < 10; ++t) {
            int i = baseA + t;
            u64 sw = __shfl(supp, i >> 6);       // uniform broadcast -> no divergence
            if (!((sw >> (i & 63)) & 1ULL)) supp |= bufA[t];
        }
        if (cc < 74) {
#pragma unroll
            for (int t = 0; t < 10; ++t)
                bufA[t] = act ? mrow[(size_t)(baseA + 20 + t) * NW + lane] : 0ULL;
        }
#pragma unroll
        for (int t = 0; t < 10; ++t) {
            int i = baseB + t;
            u64 sw = __shfl(supp, i >> 6);
            if (!((sw >> (i & 63)) & 1ULL)) supp |= bufB[t];
        }
    }

    // compaction
    u64 keepw = act ? ~supp : 0ULL;              // bits >=1500 already 0 via ~valid
    int cnt = __popcll(keepw);
    int pre = cnt;
#pragma unroll
    for (int d = 1; d < 64; d <<= 1) {
        int o = __shfl_up(pre, d);
        if (lane >= d) pre += o;
    }
    int rbase = pre - cnt;                       // exclusive prefix
    u64 m = keepw;
    int idx = 0;
    while (m) {
        int l = __ffsll((long long)m) - 1;
        m &= m - 1;
        int r = rbase + idx; ++idx;
        if (r < MAXDET) {
            int j = lane * 64 + l;
            float4 bx = tbox[b * TOPK + j];
            float sc = tsc[b * TOPK + j];
            int c = tcl[b * TOPK + j];
            float* o6 = outb + r * 6;
            o6[0] = bx.x; o6[1] = bx.y; o6[2] = bx.z; o6[3] = bx.w;
            o6[4] = sc;   o6[5] = (float)c;
        }
    }
}

// ---------------------------------------------------------------------------
extern "C" void kernel_launch(void* const* d_in, const int* in_sizes, int n_in,
                              void* d_out, int out_size, void* d_ws, size_t ws_size,
                              hipStream_t stream) {
    const float* pred = (const float*)d_in[0];
    float* out = (float*)d_out;
    char* ws = (char*)d_ws;
    if (ws_size < WS_NEED) return;   // insufficient scratch; avoid OOB writes

    u64*    keys = (u64*)   (ws + OFF_KEYS);
    int*    cls  = (int*)   (ws + OFF_CLS);
    float4* tbox = (float4*)(ws + OFF_TBOX);
    float4* tnms = (float4*)(ws + OFF_TNMS);
    float*  tsc  = (float*) (ws + OFF_TSC);
    int*    tcl  = (int*)   (ws + OFF_TCL);
    u64*    mask = (u64*)   (ws + OFF_MASK);

    k_score<<<dim3((NA + 255) / 256, NIMG), 256, 0, stream>>>(pred, cls, keys);
    k_sort_gather<<<NIMG, 1024, 0, stream>>>(pred, cls, keys, tbox, tnms, tsc, tcl);
    k_mask<<<dim3(12, NIMG), 256, 0, stream>>>(tnms, mask);
    k_scan<<<NIMG, 64, 0, stream>>>(mask, tbox, tsc, tcl, out);
}

// Round 3
// 462.590 us; speedup vs baseline: 1.2286x; 1.2286x over previous
//
#include <hip/hip_runtime.h>
#include <stdint.h>

typedef unsigned long long u64;
typedef unsigned int u32;

#define NCLS 80
#define NA   8400
#define NIMG 32
#define TOPK 1500
#define MAXDET 300
#define NW 24              // ceil(1500/64) words per suppression row
#define CONF 0.25f
#define IOU_TH 0.45f

#define CHUNK 2048         // per-block sort size
#define NCH   5            // ceil(8400/2048) -> covers 10240
#define CAND  1500         // sorted candidates kept per chunk

// ---- workspace layout (bytes) ----
#define OFF_CAND   ((size_t)0)                             // NIMG*NCH*CAND*8 (~1.9MB)
#define OFF_TBOX   (OFF_CAND + (size_t)NIMG*NCH*CAND*8)    // NIMG*TOPK*16
#define OFF_TNMS   (OFF_TBOX + (size_t)NIMG*TOPK*16)       // NIMG*TOPK*16
#define OFF_TSC    (OFF_TNMS + (size_t)NIMG*TOPK*16)       // NIMG*TOPK*4
#define OFF_TCL    (OFF_TSC  + (size_t)NIMG*TOPK*4)        // NIMG*TOPK*4
#define OFF_MASK   (OFF_TCL  + (size_t)NIMG*TOPK*4)        // NIMG*TOPK*NW*8 (~9.2MB)
#define WS_NEED    (OFF_MASK + (size_t)NIMG*TOPK*NW*8)     // ~12.5MB

// key = [~ordered(msc):32][anchor:14][cls:7][0:11]
// ascending key == descending score, ties by ascending anchor (lax.top_k exact).

// ---------------------------------------------------------------------------
// Kernel 1: fused score/argmax + chunk bitonic sort (2048/block, 1 cmp/thr/pass).
// grid (NCH, NIMG) x 1024 threads, 16 KiB LDS.
// ---------------------------------------------------------------------------
__global__ __launch_bounds__(1024) void k_sortchunk(const float* __restrict__ pred,
                                                    u64* __restrict__ cand) {
    __shared__ u64 s[CHUNK];
    const int tid = threadIdx.x;
    const int c = blockIdx.x;
    const int b = blockIdx.y;
    const int a0 = c * CHUNK;
    const float* pb = pred + (size_t)b * (4 + NCLS) * NA;

    for (int i = tid; i < CHUNK; i += 1024) {
        int a = a0 + i;
        u64 key = ~0ULL;
        if (a < NA) {
            float best = pb[(size_t)4 * NA + a];
            int bi = 0;
#pragma unroll 8
            for (int cc = 1; cc < NCLS; ++cc) {
                float v = pb[(size_t)(4 + cc) * NA + a];
                if (v > best) { best = v; bi = cc; }   // strict >: first max (jnp.argmax)
            }
            float msc = (best > CONF) ? best : -1.0f;
            u32 u = __float_as_uint(msc);
            u = (u & 0x80000000u) ? ~u : (u | 0x80000000u);
            key = ((u64)(~u) << 32) | ((u64)(u32)a << 18) | ((u64)(u32)bi << 11);
        }
        s[i] = key;
    }
    __syncthreads();

    for (u32 k = 2; k <= CHUNK; k <<= 1) {
        for (u32 j = k >> 1; j > 0; j >>= 1) {
            int t = tid;                          // exactly CHUNK/2 = 1024 slots
            int i = 2 * t - (t & (j - 1));
            u64 x = s[i], y = s[i + j];
            bool asc = (i & k) == 0;
            if ((x > y) == asc) { s[i] = y; s[i + j] = x; }
            __syncthreads();
        }
    }

    u64* cb = cand + ((size_t)b * NCH + c) * CAND;
    for (int i = tid; i < CAND; i += 1024) cb[i] = s[i];
}

// ---------------------------------------------------------------------------
// Kernel 2: merge 5 sorted candidate lists -> exact top-1500, then gather.
// Half-cleaner merge-split (lo[i]=min(A[i],B[n-1-i]) = n smallest, bitonic)
// + 11-pass bitonic merge, repeated 4x. One block per image.
// fp contract OFF: nmsbox mul+add must round like XLA's separate ops.
// ---------------------------------------------------------------------------
__global__ __launch_bounds__(1024) void k_merge_gather(const float* __restrict__ pred,
                                                       const u64* __restrict__ cand,
                                                       float4* __restrict__ tbox,
                                                       float4* __restrict__ tnms,
                                                       float* __restrict__ tsc,
                                                       int* __restrict__ tcl) {
#pragma clang fp contract(off)
    __shared__ u64 sA[CHUNK];
    __shared__ u64 sB[CHUNK];
    const int tid = threadIdx.x;
    const int b = blockIdx.x;
    const u64* cb = cand + (size_t)b * NCH * CAND;

    for (int i = tid; i < CHUNK; i += 1024)
        sA[i] = (i < CAND) ? cb[i] : ~0ULL;

    for (int m = 1; m < NCH; ++m) {
        for (int i = tid; i < CHUNK; i += 1024)
            sB[i] = (i < CAND) ? cb[(size_t)m * CAND + i] : ~0ULL;
        __syncthreads();
        for (int i = tid; i < CHUNK; i += 1024) {     // merge-split: keep lo half
            u64 x = sA[i], y = sB[CHUNK - 1 - i];
            sA[i] = (x < y) ? x : y;
        }
        __syncthreads();
        for (u32 j = CHUNK >> 1; j > 0; j >>= 1) {    // bitonic merge ascending
            int t = tid;
            int i = 2 * t - (t & (j - 1));
            u64 x = sA[i], y = sA[i + j];
            if (x > y) { sA[i] = y; sA[i + j] = x; }
            __syncthreads();
        }
    }

    const float* pb = pred + (size_t)b * (4 + NCLS) * NA;
    const float C1 = (float)((1.0 / 80.0) / 640.0);   // mult / IMGSZ
    const float C2 = (float)(1.0 / 80.0);             // mult
    for (int r = tid; r < TOPK; r += 1024) {
        u64 key = sA[r];
        int a = (int)((key >> 18) & 0x3FFFu);
        int cl = (int)((key >> 11) & 0x7Fu);
        u32 ou = ~((u32)(key >> 32));
        u32 fb = (ou & 0x80000000u) ? (ou ^ 0x80000000u) : ~ou;
        float msc = __uint_as_float(fb);
        float x1 = pb[a], y1 = pb[NA + a], x2 = pb[2 * NA + a], y2 = pb[3 * NA + a];
        float off = (float)cl * C2;
        tbox[b * TOPK + r] = make_float4(x1, y1, x2, y2);
        tnms[b * TOPK + r] = make_float4(x1 * C1 + off, y1 * C1 + off,
                                         x2 * C1 + off, y2 * C1 + off);
        tsc[b * TOPK + r] = msc;                      // == raw score whenever valid
        tcl[b * TOPK + r] = cl;
    }
}

// ---------------------------------------------------------------------------
// Kernel 3: suppression bit matrix. mask[i][w] bit l = (iou(i, w*64+l) > TH)
// for j > i. grid (12, NIMG), 125 rows per block, nms boxes cached in LDS.
// fp contract OFF (XLA rounds each op separately).
// ---------------------------------------------------------------------------
__global__ __launch_bounds__(256) void k_mask(const float4* __restrict__ tnms,
                                              u64* __restrict__ mask) {
#pragma clang fp contract(off)
    __shared__ float4 nb[TOPK];                  // 24 KB
    const int b = blockIdx.y;
    const int tid = threadIdx.x;
    for (int i = tid; i < TOPK; i += 256) nb[i] = tnms[b * TOPK + i];
    __syncthreads();

    const int row0 = blockIdx.x * 125;
    for (int item = tid; item < 125 * NW; item += 256) {
        int r = row0 + item / NW;
        int w = item % NW;
        u64 bits = 0ULL;
        if (w * 64 + 63 > r) {                   // word has any j > r
            float4 bi = nb[r];
            float area_i = (bi.z - bi.x) * (bi.w - bi.y);
            int jmax = min(64, TOPK - w * 64);
            for (int l = 0; l < jmax; ++l) {
                int j = w * 64 + l;
                if (j > r) {
                    float4 bj = nb[j];
                    float lx = fmaxf(bi.x, bj.x), ly = fmaxf(bi.y, bj.y);
                    float rx = fminf(bi.z, bj.z), ry = fminf(bi.w, bj.w);
                    float iw = fmaxf(rx - lx, 0.0f), ih = fmaxf(ry - ly, 0.0f);
                    float inter = iw * ih;
                    float area_j = (bj.z - bj.x) * (bj.w - bj.y);
                    float iou = inter / (area_i + area_j - inter + 1e-7f);
                    if (iou > IOU_TH) bits |= (1ULL << l);
                }
            }
        }
        mask[((size_t)b * TOPK + r) * NW + w] = bits;
    }
}

// ---------------------------------------------------------------------------
// Kernel 4: per-image serial greedy scan (1 wave). Lane w owns supp word w.
// supp initialized to ~valid so keep_i = !bit(supp,i) is the full condition.
// Mask rows prefetched in 10-row double-buffered register chunks.
// Then popcount prefix-sum compaction -> first min(kept,300) rows; rest zero.
// ---------------------------------------------------------------------------
__global__ __launch_bounds__(64) void k_scan(const u64* __restrict__ mask,
                                             const float4* __restrict__ tbox,
                                             const float* __restrict__ tsc,
                                             const int* __restrict__ tcl,
                                             float* __restrict__ out) {
    const int b = blockIdx.x;
    const int lane = threadIdx.x;
    float* outb = out + (size_t)b * MAXDET * 6;
    for (int i = lane; i < MAXDET * 6; i += 64) outb[i] = 0.0f;
    __syncthreads();

    u64 validw = 0ULL;
    const bool act = lane < NW;
    if (act) {
        for (int l = 0; l < 64; ++l) {
            int j = lane * 64 + l;
            if (j < TOPK && tsc[b * TOPK + j] > CONF) validw |= (1ULL << l);
        }
    }
    u64 supp = ~validw;

    const u64* mrow = mask + (size_t)b * TOPK * NW;
    u64 bufA[10], bufB[10];
#pragma unroll
    for (int t = 0; t < 10; ++t) bufA[t] = act ? mrow[(size_t)t * NW + lane] : 0ULL;

    for (int cc = 0; cc < 75; ++cc) {
        const int baseA = cc * 20;
        const int baseB = baseA + 10;
#pragma unroll
        for (int t = 0; t < 10; ++t)
            bufB[t] = act ? mrow[(size_t)(baseB + t) * NW + lane] : 0ULL;
#pragma unroll
        for (int t = 0; t < 10; ++t) {
            int i = baseA + t;
            u64 sw = __shfl(supp, i >> 6);
            if (!((sw >> (i & 63)) & 1ULL)) supp |= bufA[t];
        }
        if (cc < 74) {
#pragma unroll
            for (int t = 0; t < 10; ++t)
                bufA[t] = act ? mrow[(size_t)(baseA + 20 + t) * NW + lane] : 0ULL;
        }
#pragma unroll
        for (int t = 0; t < 10; ++t) {
            int i = baseB + t;
            u64 sw = __shfl(supp, i >> 6);
            if (!((sw >> (i & 63)) & 1ULL)) supp |= bufB[t];
        }
    }

    u64 keepw = act ? ~supp : 0ULL;
    int cnt = __popcll(keepw);
    int pre = cnt;
#pragma unroll
    for (int d = 1; d < 64; d <<= 1) {
        int o = __shfl_up(pre, d);
        if (lane >= d) pre += o;
    }
    int rbase = pre - cnt;
    u64 m = keepw;
    int idx = 0;
    while (m) {
        int l = __ffsll((long long)m) - 1;
        m &= m - 1;
        int r = rbase + idx; ++idx;
        if (r < MAXDET) {
            int j = lane * 64 + l;
            float4 bx = tbox[b * TOPK + j];
            float sc = tsc[b * TOPK + j];
            int c = tcl[b * TOPK + j];
            float* o6 = outb + r * 6;
            o6[0] = bx.x; o6[1] = bx.y; o6[2] = bx.z; o6[3] = bx.w;
            o6[4] = sc;   o6[5] = (float)c;
        }
    }
}

// ---------------------------------------------------------------------------
extern "C" void kernel_launch(void* const* d_in, const int* in_sizes, int n_in,
                              void* d_out, int out_size, void* d_ws, size_t ws_size,
                              hipStream_t stream) {
    const float* pred = (const float*)d_in[0];
    float* out = (float*)d_out;
    char* ws = (char*)d_ws;
    if (ws_size < WS_NEED) return;

    u64*    cand = (u64*)   (ws + OFF_CAND);
    float4* tbox = (float4*)(ws + OFF_TBOX);
    float4* tnms = (float4*)(ws + OFF_TNMS);
    float*  tsc  = (float*) (ws + OFF_TSC);
    int*    tcl  = (int*)   (ws + OFF_TCL);
    u64*    mask = (u64*)   (ws + OFF_MASK);

    k_sortchunk<<<dim3(NCH, NIMG), 1024, 0, stream>>>(pred, cand);
    k_merge_gather<<<NIMG, 1024, 0, stream>>>(pred, cand, tbox, tnms, tsc, tcl);
    k_mask<<<dim3(12, NIMG), 256, 0, stream>>>(tnms, mask);
    k_scan<<<NIMG, 64, 0, stream>>>(mask, tbox, tsc, tcl, out);
}